// Round 4
// baseline (168.801 us; speedup 1.0000x reference)
//
#include <hip/hip_runtime.h>
#include <hip/hip_fp16.h>

// Problem: inputs (8, 64, 16, 32, 32) fp32, embedding (1024, 64) fp32
#define THW    16384
#define NTOT   131072
#define KDIM   1024
#define CDIM   64
#define QELEMS 8388608          // 8*64*16*32*32
#define LOSS_OFF 8388608
#define IDX_OFF  8388610
#define BN     128              // queries per block

typedef _Float16 half8  __attribute__((ext_vector_type(8)));
typedef _Float16 half4_t __attribute__((ext_vector_type(4)));
typedef float    f32x4  __attribute__((ext_vector_type(4)));

// ---- prep: zero losses; split E into fp16 hi/lo (lo scaled 2^12) in
// FRAGMENT-MAJOR order (the exact per-lane order the 16x16x32 A-operand
// consumes): flat index ((tile*2 + kHalf)*64 + lane)*8 + j, where
// lane = lq*16 + ln, code row = tile*16 + ln, c = kHalf*32 + lq*8 + j.
// Also ||e||^2. grid 64 x 256: block = one 16-row tile.
__global__ __launch_bounds__(256) void vq_prep(const float* __restrict__ emb,
        _Float16* __restrict__ EhF, _Float16* __restrict__ ElF,
        float* __restrict__ e2, float* __restrict__ out) {
    const int t = threadIdx.x;
    if (blockIdx.x == 0 && t == 0) { out[LOSS_OFF] = 0.f; out[LOSS_OFF + 1] = 0.f; }
    const int ln   = t >> 4;                 // code row within tile
    const int g    = t & 15;                 // c-group of 4
    const int tile = blockIdx.x;
    const int row  = tile * 16 + ln;
    const int c0   = g * 4;
    float4 v = *(const float4*)(emb + (size_t)row * CDIM + c0);
    const float xs[4] = {v.x, v.y, v.z, v.w};
    half4_t h, l;
    float s = 0.f;
    #pragma unroll
    for (int j = 0; j < 4; ++j) {
        const _Float16 hj = (_Float16)xs[j];
        const _Float16 lj = (_Float16)((xs[j] - (float)hj) * 4096.0f);
        h[j] = hj; l[j] = lj;
        s = fmaf(xs[j], xs[j], s);
    }
    const int ch = c0 >> 5;
    const int lq = (c0 & 31) >> 3;
    const int j0 = c0 & 7;                   // 0 or 4
    const size_t dst = (((size_t)tile * 2 + ch) * 64 + (lq * 16 + ln)) * 8 + j0;
    *(half4_t*)(EhF + dst) = h;
    *(half4_t*)(ElF + dst) = l;
    #pragma unroll
    for (int off = 1; off < 16; off <<= 1) s += __shfl_xor(s, off, 64);
    if (g == 0) e2[row] = s;
}

// ---- main: barrier-free fp16x2 MFMA k-loop fed by coalesced L2 reads ----
__global__ __launch_bounds__(256, 4) void vq_main(const float* __restrict__ in,
        const float* __restrict__ emb,
        const _Float16* __restrict__ EhF, const _Float16* __restrict__ ElF,
        const float* __restrict__ e2, float* __restrict__ out) {

    // LDS: Xs[128][68] fp32 (pre / aliased in post), x2p, idxs
    __shared__ char smem[36352];
    float (*Xs)[68] = (float (*)[68])smem;                 // [128][68]
    float (*Q)[68]  = (float (*)[68])smem;                 // epilogue alias
    float* mv  = (float*)smem;                             // [2][128] alias
    int*   mi  = (int*)(smem + 1024);                      // [2][128] alias
    float* x2p = (float*)(smem + 34816);                   // [2][128]
    int*   idxs = (int*)(smem + 34816 + 1024);             // [128]

    const int tid  = threadIdx.x;
    const int n0   = blockIdx.x * BN;
    const int bb   = n0 >> 14;
    const int thw0 = n0 & (THW - 1);
    const float* inb = in  + (size_t)bb * CDIM * THW + thw0;
    float*      outb = out + (size_t)bb * CDIM * THW + thw0;

    // ---- stage X tile (fp32, transposed to [n][c]) + ||x||^2 partials ----
    {
        const int nl = tid & 127;
        const int hf = tid >> 7;
        float s = 0.f;
        #pragma unroll 8
        for (int r = 0; r < 32; ++r) {
            const int c = hf * 32 + r;
            const float x = inb[(size_t)c * THW + nl];
            Xs[nl][c] = x;
            s = fmaf(x, x, s);
        }
        x2p[hf * 128 + nl] = s;
    }
    __syncthreads();

    const int lane = tid & 63;
    const int w    = tid >> 6;
    const int ln   = lane & 15;
    const int lq   = lane >> 4;
    const int qb   = (w >> 1) * 64;     // query-half base for this wave
    const int cw   = (w & 1) * 2;       // code-tile pair within each group of 4

    // ---- build X fragments (fp16 hi/lo), register-resident all k-loop ----
    half8 Bh[4][2], Bl[4][2];
    #pragma unroll
    for (int qg = 0; qg < 4; ++qg) {
        const int q = qb + qg * 16 + ln;
        #pragma unroll
        for (int ch = 0; ch < 2; ++ch) {
            const float* xp = &Xs[q][ch * 32 + lq * 8];
            const float4 xa = *(const float4*)(xp);
            const float4 xb = *(const float4*)(xp + 4);
            const float xv[8] = {xa.x, xa.y, xa.z, xa.w, xb.x, xb.y, xb.z, xb.w};
            #pragma unroll
            for (int j = 0; j < 8; ++j) {
                const _Float16 h = (_Float16)xv[j];
                const _Float16 l = (_Float16)((xv[j] - (float)h) * 4096.0f);
                Bh[qg][ch][j] = h;
                Bl[qg][ch][j] = l;
            }
        }
    }
    __syncthreads();   // all waves done reading Xs before mv/mi alias writes later

    float bestv[4];
    int   besti[4];
    #pragma unroll
    for (int qg = 0; qg < 4; ++qg) { bestv[qg] = 3.4e38f; besti[qg] = 0; }

    // ---- barrier-free k-loop: 64 code tiles, this wave does 32 of them ----
    for (int tb = 0; tb < 16; ++tb) {
        #pragma unroll
        for (int cc = 0; cc < 2; ++cc) {
            const int t = tb * 4 + cw + cc;
            const half8* ph = (const half8*)(EhF + ((size_t)t * 2) * 64 * 8);
            const half8* pl = (const half8*)(ElF + ((size_t)t * 2) * 64 * 8);
            const half8 Ah0 = ph[lane];
            const half8 Ah1 = ph[64 + lane];
            const half8 Al0 = pl[lane];
            const half8 Al1 = pl[64 + lane];
            const float4 e2v = *(const float4*)(e2 + t * 16 + lq * 4);
            const float e2a[4] = {e2v.x, e2v.y, e2v.z, e2v.w};
            #pragma unroll
            for (int qg = 0; qg < 4; ++qg) {
                f32x4 a0 = {0.f, 0.f, 0.f, 0.f};
                f32x4 a1 = {0.f, 0.f, 0.f, 0.f};
                a0 = __builtin_amdgcn_mfma_f32_16x16x32_f16(Ah0, Bh[qg][0], a0, 0, 0, 0);
                a0 = __builtin_amdgcn_mfma_f32_16x16x32_f16(Ah1, Bh[qg][1], a0, 0, 0, 0);
                a1 = __builtin_amdgcn_mfma_f32_16x16x32_f16(Ah0, Bl[qg][0], a1, 0, 0, 0);
                a1 = __builtin_amdgcn_mfma_f32_16x16x32_f16(Al0, Bh[qg][0], a1, 0, 0, 0);
                a1 = __builtin_amdgcn_mfma_f32_16x16x32_f16(Ah1, Bl[qg][1], a1, 0, 0, 0);
                a1 = __builtin_amdgcn_mfma_f32_16x16x32_f16(Al1, Bh[qg][1], a1, 0, 0, 0);
                // d = ||e||^2 - 2*(a0 + 2^-12 * a1)
                #pragma unroll
                for (int r = 0; r < 4; ++r) {
                    const float d = fmaf(-2.0f, a0[r], fmaf(-4.8828125e-4f, a1[r], e2a[r]));
                    const int kg = t * 16 + lq * 4 + r;
                    if (d < bestv[qg]) { bestv[qg] = d; besti[qg] = kg; }
                }
            }
        }
    }

    // ---- wave-internal argmin reduce across the 4 row-quads ----
    #pragma unroll
    for (int qg = 0; qg < 4; ++qg) {
        #pragma unroll
        for (int m = 16; m <= 32; m <<= 1) {
            const float ov = __shfl_xor(bestv[qg], m, 64);
            const int   oi = __shfl_xor(besti[qg], m, 64);
            if (ov < bestv[qg] || (ov == bestv[qg] && oi < besti[qg])) {
                bestv[qg] = ov; besti[qg] = oi;
            }
        }
    }
    if (lq == 0) {
        #pragma unroll
        for (int qg = 0; qg < 4; ++qg) {
            const int q = qb + qg * 16 + ln;
            mv[(w & 1) * 128 + q] = bestv[qg];
            mi[(w & 1) * 128 + q] = besti[qg];
        }
    }
    __syncthreads();

    // ---- merge code-halves; write indices; loss = sum(bestd + ||x||^2) ----
    float lsum = 0.f;
    if (tid < 128) {
        const int q = tid;
        float v0 = mv[q]; int i0 = mi[q];
        const float v1 = mv[128 + q]; const int i1 = mi[128 + q];
        if (v1 < v0 || (v1 == v0 && i1 < i0)) { v0 = v1; i0 = i1; }
        idxs[q] = i0;
        out[IDX_OFF + n0 + q] = (float)i0;
        lsum = v0 + x2p[q] + x2p[128 + q];
    }
    #pragma unroll
    for (int off = 32; off > 0; off >>= 1) lsum += __shfl_down(lsum, off, 64);
    if (lane == 0 && w < 2) {
        atomicAdd(&out[LOSS_OFF],     lsum * (1.0f  / (float)QELEMS));
        atomicAdd(&out[LOSS_OFF + 1], lsum * (0.25f / (float)QELEMS));
    }
    __syncthreads();

    // ---- epilogue: gather code rows coalesced into LDS, transpose-write ----
    {
        const int q  = tid >> 1;
        const int hf = tid & 1;
        const float* er = emb + (size_t)idxs[q] * CDIM + hf * 32;
        #pragma unroll
        for (int j = 0; j < 8; ++j) {
            const float4 v = *(const float4*)(er + 4 * j);
            *(float4*)(&Q[q][hf * 32 + 4 * j]) = v;
        }
    }
    __syncthreads();
    {
        const int nl = tid & 127;
        const int cb = tid >> 7;
        #pragma unroll 8
        for (int r = 0; r < 32; ++r) {
            const int c = 2 * r + cb;
            outb[(size_t)c * THW + nl] = Q[nl][c];
        }
    }
}

extern "C" void kernel_launch(void* const* d_in, const int* in_sizes, int n_in,
                              void* d_out, int out_size, void* d_ws, size_t ws_size,
                              hipStream_t stream) {
    const float* in  = (const float*)d_in[0];   // (8, 64, 16, 32, 32) fp32
    const float* emb = (const float*)d_in[1];   // (1024, 64) fp32
    float* out = (float*)d_out;
    _Float16* EhF = (_Float16*)d_ws;                        // 64 tiles * 2 * 64 lanes * 8
    _Float16* ElF = (_Float16*)((char*)d_ws + 131072);
    float*    e2  = (float*)((char*)d_ws + 262144);         // 1024 floats

    vq_prep<<<KDIM / 16, 256, 0, stream>>>(emb, EhF, ElF, e2, out);
    vq_main<<<NTOT / BN, 256, 0, stream>>>(in, emb, EhF, ElF, e2, out);
}

// Round 5
// 159.151 us; speedup vs baseline: 1.0606x; 1.0606x over previous
//
#include <hip/hip_runtime.h>
#include <hip/hip_fp16.h>

// Problem: inputs (8, 64, 16, 32, 32) fp32, embedding (1024, 64) fp32
#define THW    16384
#define NTOT   131072
#define KDIM   1024
#define CDIM   64
#define QELEMS 8388608          // 8*64*16*32*32
#define LOSS_OFF 8388608
#define IDX_OFF  8388610
#define BN     64               // queries per block

typedef _Float16 half8   __attribute__((ext_vector_type(8)));
typedef _Float16 half4_t __attribute__((ext_vector_type(4)));
typedef float    f32x4   __attribute__((ext_vector_type(4)));

// ---- prep: zero losses; split E into fp16 hi/lo (lo scaled 2^12) in
// fragment-major order: flat ((tile*2 + kHalf)*64 + lane)*8 + j, where
// lane = lq*16 + ln, code row = tile*16 + ln, c = kHalf*32 + lq*8 + j.
__global__ __launch_bounds__(256) void vq_prep(const float* __restrict__ emb,
        _Float16* __restrict__ EhF, _Float16* __restrict__ ElF,
        float* __restrict__ e2, float* __restrict__ out) {
    const int t = threadIdx.x;
    if (blockIdx.x == 0 && t == 0) { out[LOSS_OFF] = 0.f; out[LOSS_OFF + 1] = 0.f; }
    const int ln   = t >> 4;
    const int g    = t & 15;
    const int tile = blockIdx.x;
    const int row  = tile * 16 + ln;
    const int c0   = g * 4;
    float4 v = *(const float4*)(emb + (size_t)row * CDIM + c0);
    const float xs[4] = {v.x, v.y, v.z, v.w};
    half4_t h, l;
    float s = 0.f;
    #pragma unroll
    for (int j = 0; j < 4; ++j) {
        const _Float16 hj = (_Float16)xs[j];
        const _Float16 lj = (_Float16)((xs[j] - (float)hj) * 4096.0f);
        h[j] = hj; l[j] = lj;
        s = fmaf(xs[j], xs[j], s);
    }
    const int ch = c0 >> 5;
    const int lq = (c0 & 31) >> 3;
    const int j0 = c0 & 7;
    const size_t dst = (((size_t)tile * 2 + ch) * 64 + (lq * 16 + ln)) * 8 + j0;
    *(half4_t*)(EhF + dst) = h;
    *(half4_t*)(ElF + dst) = l;
    #pragma unroll
    for (int off = 1; off < 16; off <<= 1) s += __shfl_xor(s, off, 64);
    if (g == 0) e2[row] = s;
}

// ---- main: double-buffered prefetch fp16x2 MFMA k-loop, BN=64 ----
__global__ __launch_bounds__(256, 4) void vq_main(const float* __restrict__ in,
        const float* __restrict__ emb,
        const _Float16* __restrict__ EhF, const _Float16* __restrict__ ElF,
        const float* __restrict__ e2, float* __restrict__ out) {

    __shared__ char smem[18688];
    float (*Xs)[68] = (float (*)[68])smem;                 // [64][68] = 17408 B
    float (*Q)[68]  = (float (*)[68])smem;                 // epilogue alias
    float* mv   = (float*)smem;                            // [2][64] alias
    int*   mi   = (int*)(smem + 512);                      // [2][64] alias
    float* x2p4 = (float*)(smem + 17408);                  // [4][64]
    int*   idxs = (int*)(smem + 18432);                    // [64]

    const int tid  = threadIdx.x;
    const int n0   = blockIdx.x * BN;
    const int bb   = n0 >> 14;
    const int thw0 = n0 & (THW - 1);
    const float* inb = in  + (size_t)bb * CDIM * THW + thw0;
    float*      outb = out + (size_t)bb * CDIM * THW + thw0;

    // ---- stage X tile ([n][c] transpose) + ||x||^2 partials ----
    {
        const int nl = tid & 63;
        const int cq = tid >> 6;               // 0..3
        float s = 0.f;
        #pragma unroll
        for (int r = 0; r < 16; ++r) {
            const int c = r * 4 + cq;
            const float x = inb[(size_t)c * THW + nl];
            Xs[nl][c] = x;
            s = fmaf(x, x, s);
        }
        x2p4[cq * 64 + nl] = s;
    }
    __syncthreads();

    const int lane = tid & 63;
    const int w    = tid >> 6;
    const int ln   = lane & 15;
    const int lq   = lane >> 4;
    const int qh   = w >> 1;        // query half: 32 queries
    const int tp   = w & 1;         // tile parity: 32 of 64 tiles

    // ---- B fragments (fp16 hi/lo), register-resident ----
    half8 Bh[2][2], Bl[2][2];
    #pragma unroll
    for (int qg = 0; qg < 2; ++qg) {
        const int q = qh * 32 + qg * 16 + ln;
        #pragma unroll
        for (int ch = 0; ch < 2; ++ch) {
            const float* xp = &Xs[q][ch * 32 + lq * 8];
            const float4 xa = *(const float4*)(xp);
            const float4 xb = *(const float4*)(xp + 4);
            const float xv[8] = {xa.x, xa.y, xa.z, xa.w, xb.x, xb.y, xb.z, xb.w};
            #pragma unroll
            for (int j = 0; j < 8; ++j) {
                const _Float16 h = (_Float16)xv[j];
                const _Float16 l = (_Float16)((xv[j] - (float)h) * 4096.0f);
                Bh[qg][ch][j] = h;
                Bl[qg][ch][j] = l;
            }
        }
    }
    __syncthreads();   // Xs dead; mv/mi alias written after k-loop

    float bestv[2] = {3.4e38f, 3.4e38f};
    int   besti[2] = {0, 0};

    const half8* ph = (const half8*)EhF + (size_t)tp * 128 + lane;
    const half8* pl = (const half8*)ElF + (size_t)tp * 128 + lane;
    const float* pe = e2 + tp * 16 + lq * 4;

    // double-buffered A-fragments + e2
    half8 Ah0[2], Ah1[2], Al0[2], Al1[2];
    float4 e2r[2];
    Ah0[0] = ph[0];  Ah1[0] = ph[64];
    Al0[0] = pl[0];  Al1[0] = pl[64];
    e2r[0] = *(const float4*)pe;

    #pragma unroll 2
    for (int m = 0; m < 32; ++m) {
        const int cur = m & 1;
        const int nxt = cur ^ 1;
        if (m < 31) {   // prefetch tile t+2 while computing t
            const size_t o = (size_t)(m + 1) * 256;
            Ah0[nxt] = ph[o];  Ah1[nxt] = ph[o + 64];
            Al0[nxt] = pl[o];  Al1[nxt] = pl[o + 64];
            e2r[nxt] = *(const float4*)(pe + (m + 1) * 32);
        }
        const int t = tp + 2 * m;
        const float e2a[4] = {e2r[cur].x, e2r[cur].y, e2r[cur].z, e2r[cur].w};
        #pragma unroll
        for (int qg = 0; qg < 2; ++qg) {
            f32x4 a0 = {0.f, 0.f, 0.f, 0.f};
            f32x4 a1 = {0.f, 0.f, 0.f, 0.f};
            a0 = __builtin_amdgcn_mfma_f32_16x16x32_f16(Ah0[cur], Bh[qg][0], a0, 0, 0, 0);
            a0 = __builtin_amdgcn_mfma_f32_16x16x32_f16(Ah1[cur], Bh[qg][1], a0, 0, 0, 0);
            a1 = __builtin_amdgcn_mfma_f32_16x16x32_f16(Ah0[cur], Bl[qg][0], a1, 0, 0, 0);
            a1 = __builtin_amdgcn_mfma_f32_16x16x32_f16(Al0[cur], Bh[qg][0], a1, 0, 0, 0);
            a1 = __builtin_amdgcn_mfma_f32_16x16x32_f16(Ah1[cur], Bl[qg][1], a1, 0, 0, 0);
            a1 = __builtin_amdgcn_mfma_f32_16x16x32_f16(Al1[cur], Bh[qg][1], a1, 0, 0, 0);
            #pragma unroll
            for (int r = 0; r < 4; ++r) {
                const float d = fmaf(-2.0f, a0[r], fmaf(-4.8828125e-4f, a1[r], e2a[r]));
                const int kg = t * 16 + lq * 4 + r;
                if (d < bestv[qg]) { bestv[qg] = d; besti[qg] = kg; }
            }
        }
    }

    // ---- wave-internal argmin reduce across the 4 row-quads ----
    #pragma unroll
    for (int qg = 0; qg < 2; ++qg) {
        #pragma unroll
        for (int msk = 16; msk <= 32; msk <<= 1) {
            const float ov = __shfl_xor(bestv[qg], msk, 64);
            const int   oi = __shfl_xor(besti[qg], msk, 64);
            if (ov < bestv[qg] || (ov == bestv[qg] && oi < besti[qg])) {
                bestv[qg] = ov; besti[qg] = oi;
            }
        }
    }
    if (lq == 0) {
        #pragma unroll
        for (int qg = 0; qg < 2; ++qg) {
            const int q = qh * 32 + qg * 16 + ln;
            mv[tp * 64 + q] = bestv[qg];
            mi[tp * 64 + q] = besti[qg];
        }
    }
    __syncthreads();

    // ---- merge tile parities; indices; loss = sum(bestd + ||x||^2) ----
    float lsum = 0.f;
    if (tid < 64) {
        const int q = tid;
        float v0 = mv[q]; int i0 = mi[q];
        const float v1 = mv[64 + q]; const int i1 = mi[64 + q];
        if (v1 < v0 || (v1 == v0 && i1 < i0)) { v0 = v1; i0 = i1; }
        idxs[q] = i0;
        out[IDX_OFF + n0 + q] = (float)i0;
        lsum = v0 + x2p4[q] + x2p4[64 + q] + x2p4[128 + q] + x2p4[192 + q];
    }
    if (w == 0) {
        #pragma unroll
        for (int off = 32; off > 0; off >>= 1) lsum += __shfl_down(lsum, off, 64);
        if (lane == 0) {
            atomicAdd(&out[LOSS_OFF],     lsum * (1.0f  / (float)QELEMS));
            atomicAdd(&out[LOSS_OFF + 1], lsum * (0.25f / (float)QELEMS));
        }
    }
    __syncthreads();

    // ---- epilogue: gather code rows into LDS, transpose-write ----
    {
        const int q    = tid >> 2;
        const int part = tid & 3;
        const float* er = emb + (size_t)idxs[q] * CDIM + part * 16;
        #pragma unroll
        for (int j = 0; j < 4; ++j) {
            const float4 v = *(const float4*)(er + 4 * j);
            *(float4*)(&Q[q][part * 16 + 4 * j]) = v;
        }
    }
    __syncthreads();
    {
        const int nl = tid & 63;
        const int cb = tid >> 6;
        #pragma unroll
        for (int r = 0; r < 16; ++r) {
            const int c = r * 4 + cb;
            outb[(size_t)c * THW + nl] = Q[nl][c];
        }
    }
}

extern "C" void kernel_launch(void* const* d_in, const int* in_sizes, int n_in,
                              void* d_out, int out_size, void* d_ws, size_t ws_size,
                              hipStream_t stream) {
    const float* in  = (const float*)d_in[0];   // (8, 64, 16, 32, 32) fp32
    const float* emb = (const float*)d_in[1];   // (1024, 64) fp32
    float* out = (float*)d_out;
    _Float16* EhF = (_Float16*)d_ws;                        // 64 tiles * 1024 halves
    _Float16* ElF = (_Float16*)((char*)d_ws + 131072);
    float*    e2  = (float*)((char*)d_ws + 262144);         // 1024 floats

    vq_prep<<<KDIM / 16, 256, 0, stream>>>(emb, EhF, ElF, e2, out);
    vq_main<<<NTOT / BN, 256, 0, stream>>>(in, emb, EhF, ElF, e2, out);
}